// Round 8
// baseline (186.215 us; speedup 1.0000x reference)
//
#include <hip/hip_runtime.h>
#include <math.h>

#define INDIM 128
#define OUTDIM 64
#define HPAD 132     // h tile row stride in floats (breaks power-of-2 bank stride)
#define SCHUNK 2048  // edges per bucket_scatter block

static __device__ __forceinline__ unsigned short f2bf(float f) {
    unsigned u = __float_as_uint(f);
    u += 0x7FFFu + ((u >> 16) & 1u);   // round-to-nearest-even
    return (unsigned short)(u >> 16);
}
static __device__ __forceinline__ float bf2f(unsigned short b) {
    return __uint_as_float((unsigned)b << 16);
}

// Kernel 1: z = h@W (z stored bf16), 64x64x128 tile, 4x4 micro-tile/thread.
// s,t computed from fp32 accumulators. Both operands in LDS.
__global__ __launch_bounds__(256) void node_transform(
    const float* __restrict__ h, const float* __restrict__ W,
    const float* __restrict__ Wa, unsigned short* __restrict__ z,
    float* __restrict__ s, float* __restrict__ t, int N)
{
    __shared__ __align__(16) float hs[64 * HPAD];
    __shared__ __align__(16) float Ws[INDIM * OUTDIM];

    int tid = threadIdx.x;
    int node0 = blockIdx.x * 64;
    int nv = min(64, N - node0);

    {
        const float4* hg = (const float4*)(h + (size_t)node0 * INDIM);
        const float4* Wg = (const float4*)W;
        float4* Ws4 = (float4*)Ws;
        #pragma unroll
        for (int i = 0; i < 8; ++i) {
            int idx = i * 256 + tid;
            int n = idx >> 5, j = idx & 31;
            float4 v = (n < nv) ? hg[n * 32 + j] : make_float4(0.f, 0.f, 0.f, 0.f);
            *(float4*)&hs[n * HPAD + j * 4] = v;
            Ws4[idx] = Wg[idx];
        }
    }
    __syncthreads();

    int fg = tid & 15, ng = tid >> 4;
    int f0 = fg * 4, tn = ng * 4;

    float acc[4][4];
    #pragma unroll
    for (int i = 0; i < 4; ++i)
        #pragma unroll
        for (int j = 0; j < 4; ++j) acc[i][j] = 0.f;

    #pragma unroll 4
    for (int k = 0; k < INDIM; k += 4) {
        float4 w0 = *(const float4*)&Ws[(k + 0) * OUTDIM + f0];
        float4 w1 = *(const float4*)&Ws[(k + 1) * OUTDIM + f0];
        float4 w2 = *(const float4*)&Ws[(k + 2) * OUTDIM + f0];
        float4 w3 = *(const float4*)&Ws[(k + 3) * OUTDIM + f0];
        float4 a0 = *(const float4*)&hs[(tn + 0) * HPAD + k];
        float4 a1 = *(const float4*)&hs[(tn + 1) * HPAD + k];
        float4 a2 = *(const float4*)&hs[(tn + 2) * HPAD + k];
        float4 a3 = *(const float4*)&hs[(tn + 3) * HPAD + k];
        #define ROW(r, ax, ay, az, aw) { \
            acc[r][0] += ax * w0.x + ay * w1.x + az * w2.x + aw * w3.x; \
            acc[r][1] += ax * w0.y + ay * w1.y + az * w2.y + aw * w3.y; \
            acc[r][2] += ax * w0.z + ay * w1.z + az * w2.z + aw * w3.z; \
            acc[r][3] += ax * w0.w + ay * w1.w + az * w2.w + aw * w3.w; }
        ROW(0, a0.x, a0.y, a0.z, a0.w)
        ROW(1, a1.x, a1.y, a1.z, a1.w)
        ROW(2, a2.x, a2.y, a2.z, a2.w)
        ROW(3, a3.x, a3.y, a3.z, a3.w)
        #undef ROW
    }

    #pragma unroll
    for (int i = 0; i < 4; ++i) {
        int node = node0 + tn + i;
        if (node < N) {
            ushort4 zb = make_ushort4(f2bf(acc[i][0]), f2bf(acc[i][1]),
                                      f2bf(acc[i][2]), f2bf(acc[i][3]));
            *(ushort4*)&z[(size_t)node * OUTDIM + f0] = zb;
        }
    }

    float4 was = *(const float4*)&Wa[f0];
    float4 wat = *(const float4*)&Wa[OUTDIM + f0];
    __syncthreads();
    float* sred = hs;
    float* tred = hs + 64;
    if (tid < 64) { sred[tid] = 0.f; tred[tid] = 0.f; }
    __syncthreads();
    #pragma unroll
    for (int i = 0; i < 4; ++i) {
        float ps = acc[i][0] * was.x + acc[i][1] * was.y +
                   acc[i][2] * was.z + acc[i][3] * was.w;
        float pt = acc[i][0] * wat.x + acc[i][1] * wat.y +
                   acc[i][2] * wat.z + acc[i][3] * wat.w;
        atomicAdd(&sred[tn + i], ps);
        atomicAdd(&tred[tn + i], pt);
    }
    __syncthreads();
    if (tid < 64 && node0 + tid < N) {
        s[node0 + tid] = sred[tid];
        t[node0 + tid] = tred[tid];
    }
}

// Kernel 2: coarse histogram of dst>>8 — LDS-local, one global atomic per bucket/block.
__global__ __launch_bounds__(256) void bucket_count(
    const int* __restrict__ dst, int* __restrict__ bcnt, int E)
{
    __shared__ int l[256];
    int tid = threadIdx.x;
    l[tid] = 0;
    __syncthreads();
    int base = blockIdx.x * 8192;
    #pragma unroll 4
    for (int u = 0; u < 32; ++u) {
        int i = base + u * 256 + tid;
        if (i < E) atomicAdd(&l[dst[i] >> 8], 1);
    }
    __syncthreads();
    if (l[tid]) atomicAdd(bcnt + tid, l[tid]);
}

// Kernel 3: single-block exclusive scan of bucket counts -> bstart[0..nbuck], gcursor.
__global__ __launch_bounds__(256) void bucket_scan(
    const int* __restrict__ bcnt, int* __restrict__ bstart,
    int* __restrict__ gcursor, int nbuck)
{
    __shared__ int tmp[256];
    int tid = threadIdx.x;
    int v = (tid < nbuck) ? bcnt[tid] : 0;
    tmp[tid] = v;
    __syncthreads();
    for (int off = 1; off < 256; off <<= 1) {
        int add = (tid >= off) ? tmp[tid - off] : 0;
        __syncthreads();
        tmp[tid] += add;
        __syncthreads();
    }
    int excl = tmp[tid] - v;
    if (tid < nbuck) { bstart[tid] = excl; gcursor[tid] = excl; }
    if (tid == 255) bstart[nbuck] = tmp[255];
}

// Kernel 4: scatter packed edges ((dst&255)<<24 | src) into bucket-contiguous regions.
// LDS reorder per block -> one global cursor atomic per bucket per block, dense writes.
__global__ __launch_bounds__(256) void bucket_scatter(
    const int* __restrict__ src, const int* __restrict__ dst,
    int* __restrict__ gcursor, int* __restrict__ esort, int E)
{
    __shared__ int lcnt[256];
    __shared__ int loff[256];
    __shared__ int gbase[256];
    __shared__ int lcur[256];
    __shared__ int stage[SCHUNK];
    __shared__ unsigned char bof[SCHUNK];
    int tid = threadIdx.x;
    int base = blockIdx.x * SCHUNK;
    int ne = min(SCHUNK, E - base);

    lcnt[tid] = 0;
    __syncthreads();

    int mys[8], myd[8];
    #pragma unroll
    for (int u = 0; u < 8; ++u) {
        int li = u * 256 + tid;
        if (li < ne) {
            mys[u] = src[base + li];
            myd[u] = dst[base + li];
            atomicAdd(&lcnt[myd[u] >> 8], 1);
        } else myd[u] = -1;
    }
    __syncthreads();

    loff[tid] = lcnt[tid];
    __syncthreads();
    for (int off = 1; off < 256; off <<= 1) {
        int add = (tid >= off) ? loff[tid - off] : 0;
        __syncthreads();
        loff[tid] += add;
        __syncthreads();
    }
    int excl = loff[tid] - lcnt[tid];
    loff[tid] = excl;
    lcur[tid] = excl;
    if (lcnt[tid] > 0) gbase[tid] = atomicAdd(gcursor + tid, lcnt[tid]);
    __syncthreads();

    #pragma unroll
    for (int u = 0; u < 8; ++u) {
        if (myd[u] >= 0) {
            int b = myd[u] >> 8;
            int p = atomicAdd(&lcur[b], 1);
            stage[p] = ((myd[u] & 255) << 24) | mys[u];
            bof[p] = (unsigned char)b;
        }
    }
    __syncthreads();

    for (int i = tid; i < ne; i += 256) {
        int b = bof[i];
        esort[gbase[b] + (i - loff[b])] = stage[i];
    }
}

// Kernel 5: one block per bucket: local histogram/scan/fill entirely in LDS.
// Emits counts[node], offsets[node], and dst-sorted srcs.
__global__ __launch_bounds__(256) void bucket_fill(
    const int* __restrict__ esort, const int* __restrict__ bstart,
    int* __restrict__ counts, int* __restrict__ offsets,
    int* __restrict__ srcs, int N)
{
    __shared__ int cnt[256];
    __shared__ int off[256];
    __shared__ int cur[256];
    int tid = threadIdx.x;
    int b = blockIdx.x;
    int e0 = bstart[b], e1 = bstart[b + 1];
    int node0 = b << 8;

    cnt[tid] = 0;
    __syncthreads();
    for (int i = e0 + tid; i < e1; i += 256)
        atomicAdd(&cnt[((unsigned)esort[i]) >> 24], 1);
    __syncthreads();

    off[tid] = cnt[tid];
    __syncthreads();
    for (int o = 1; o < 256; o <<= 1) {
        int add = (tid >= o) ? off[tid - o] : 0;
        __syncthreads();
        off[tid] += add;
        __syncthreads();
    }
    int excl = off[tid] - cnt[tid];
    cur[tid] = excl;
    int node = node0 + tid;
    if (node < N) { counts[node] = cnt[tid]; offsets[node] = e0 + excl; }
    __syncthreads();

    for (int i = e0 + tid; i < e1; i += 256) {
        int pe = esort[i];
        int p = atomicAdd(&cur[((unsigned)pe) >> 24], 1);
        srcs[e0 + p] = pe & 0xFFFFFF;
    }
}

// Kernel 6: one wave per dst node: softmax over incoming edges + weighted bf16 gather.
__global__ __launch_bounds__(256) void aggregate(
    const unsigned short* __restrict__ z, const int* __restrict__ srcs,
    const float* __restrict__ s, const float* __restrict__ t,
    const int* __restrict__ offsets, const int* __restrict__ counts,
    float* __restrict__ out, int N)
{
    int wave = threadIdx.x >> 6;
    int lane = threadIdx.x & 63;
    int node = blockIdx.x * 4 + wave;
    if (node >= N) return;
    int start = offsets[node];
    int deg = counts[node];
    size_t orow = (size_t)node * OUTDIM + lane;
    if (deg == 0) { out[orow] = 0.f; return; }
    float tn = t[node];

    if (deg <= 64) {
        int sn = 0; float ev = 0.f;
        if (lane < deg) { sn = srcs[start + lane]; ev = fmaxf(s[sn] + tn, 0.f); }
        float mx = ev;
        #pragma unroll
        for (int off = 32; off; off >>= 1) mx = fmaxf(mx, __shfl_xor(mx, off, 64));
        float ex = (lane < deg) ? __expf(ev - mx) : 0.f;
        float se = ex;
        #pragma unroll
        for (int off = 32; off; off >>= 1) se += __shfl_xor(se, off, 64);

        float acc = 0.f;
        int j = 0;
        for (; j + 8 <= deg; j += 8) {
            int si[8]; float ei[8]; unsigned short ai[8];
            #pragma unroll
            for (int u = 0; u < 8; ++u) {
                si[u] = __shfl(sn, j + u, 64);
                ei[u] = __shfl(ex, j + u, 64);
            }
            #pragma unroll
            for (int u = 0; u < 8; ++u)
                ai[u] = z[(size_t)si[u] * OUTDIM + lane];
            #pragma unroll
            for (int u = 0; u < 8; ++u)
                acc += ei[u] * bf2f(ai[u]);
        }
        for (; j + 4 <= deg; j += 4) {
            int s0 = __shfl(sn, j, 64),     s1 = __shfl(sn, j + 1, 64);
            int s2 = __shfl(sn, j + 2, 64), s3 = __shfl(sn, j + 3, 64);
            float e0 = __shfl(ex, j, 64),     e1 = __shfl(ex, j + 1, 64);
            float e2 = __shfl(ex, j + 2, 64), e3 = __shfl(ex, j + 3, 64);
            float a0 = bf2f(z[(size_t)s0 * OUTDIM + lane]);
            float a1 = bf2f(z[(size_t)s1 * OUTDIM + lane]);
            float a2 = bf2f(z[(size_t)s2 * OUTDIM + lane]);
            float a3 = bf2f(z[(size_t)s3 * OUTDIM + lane]);
            acc += e0 * a0; acc += e1 * a1; acc += e2 * a2; acc += e3 * a3;
        }
        for (; j < deg; ++j) {
            int sj = __shfl(sn, j, 64);
            float ej = __shfl(ex, j, 64);
            acc += ej * bf2f(z[(size_t)sj * OUTDIM + lane]);
        }
        out[orow] = fmaxf(acc / se, 0.f);
    } else {
        float mx = 0.f;
        for (int j = lane; j < deg; j += 64) {
            int sj = srcs[start + j];
            mx = fmaxf(mx, fmaxf(s[sj] + tn, 0.f));
        }
        #pragma unroll
        for (int off = 32; off; off >>= 1) mx = fmaxf(mx, __shfl_xor(mx, off, 64));
        float se = 0.f;
        for (int j = lane; j < deg; j += 64) {
            int sj = srcs[start + j];
            se += __expf(fmaxf(s[sj] + tn, 0.f) - mx);
        }
        #pragma unroll
        for (int off = 32; off; off >>= 1) se += __shfl_xor(se, off, 64);
        float acc = 0.f;
        for (int j = 0; j < deg; ++j) {
            int sj = srcs[start + j];
            float ej = __expf(fmaxf(s[sj] + tn, 0.f) - mx);
            acc += ej * bf2f(z[(size_t)sj * OUTDIM + lane]);
        }
        out[orow] = fmaxf(acc / se, 0.f);
    }
}

extern "C" void kernel_launch(void* const* d_in, const int* in_sizes, int n_in,
                              void* d_out, int out_size, void* d_ws, size_t ws_size,
                              hipStream_t stream) {
    const float* h  = (const float*)d_in[0];
    const float* W  = (const float*)d_in[1];
    const float* Wa = (const float*)d_in[2];
    const int* src  = (const int*)d_in[3];
    const int* dst  = (const int*)d_in[4];
    int N = in_sizes[0] / INDIM;
    int E = in_sizes[3];
    float* out = (float*)d_out;
    int nbuck = (N + 255) >> 8;   // <= 256 (N <= 65536)

    char* ws = (char*)d_ws;
    unsigned short* z = (unsigned short*)ws;  ws += (size_t)N * OUTDIM * 2;
    float* s       = (float*)ws;  ws += (size_t)N * 4;
    float* t       = (float*)ws;  ws += (size_t)N * 4;
    int*   srcs    = (int*)ws;    ws += (size_t)E * 4;
    int*   counts  = (int*)ws;    ws += (size_t)N * 4;
    int*   offsets = (int*)ws;    ws += (size_t)N * 4;
    int*   esort   = (int*)ws;    ws += (size_t)E * 4;
    int*   bcnt    = (int*)ws;    ws += 256 * 4;
    int*   bstart  = (int*)ws;    ws += 260 * 4;
    int*   gcursor = (int*)ws;    ws += 256 * 4;

    hipMemsetAsync(bcnt, 0, 256 * sizeof(int), stream);

    node_transform<<<(N + 63) / 64, 256, 0, stream>>>(h, W, Wa, z, s, t, N);
    bucket_count<<<(E + 8191) / 8192, 256, 0, stream>>>(dst, bcnt, E);
    bucket_scan<<<1, 256, 0, stream>>>(bcnt, bstart, gcursor, nbuck);
    bucket_scatter<<<(E + SCHUNK - 1) / SCHUNK, 256, 0, stream>>>(src, dst, gcursor, esort, E);
    bucket_fill<<<nbuck, 256, 0, stream>>>(esort, bstart, counts, offsets, srcs, N);
    aggregate<<<(N + 3) / 4, 256, 0, stream>>>(z, srcs, s, t, offsets, counts, out, N);
}

// Round 9
// 169.761 us; speedup vs baseline: 1.0969x; 1.0969x over previous
//
#include <hip/hip_runtime.h>
#include <math.h>

#define INDIM 128
#define OUTDIM 64
#define HPAD 132     // h tile row stride in floats (breaks power-of-2 bank stride)
#define SCHUNK 2048  // edges per bucket_scatter block

static __device__ __forceinline__ unsigned short f2bf(float f) {
    unsigned u = __float_as_uint(f);
    u += 0x7FFFu + ((u >> 16) & 1u);   // round-to-nearest-even
    return (unsigned short)(u >> 16);
}
static __device__ __forceinline__ float bf2f(unsigned short b) {
    return __uint_as_float((unsigned)b << 16);
}

// Kernel 1 (fused): blocks [0,gemm_blocks): z = h@W (bf16 out) + s,t epilogue.
// Blocks >= gemm_blocks: LDS-local coarse histogram of dst>>8.
__global__ __launch_bounds__(256) void nt_count(
    const float* __restrict__ h, const float* __restrict__ W,
    const float* __restrict__ Wa, unsigned short* __restrict__ z,
    float* __restrict__ s, float* __restrict__ t,
    const int* __restrict__ dst, int* __restrict__ bcnt,
    int N, int E, int gemm_blocks)
{
    __shared__ __align__(16) float hs[64 * HPAD];
    __shared__ __align__(16) float Ws[INDIM * OUTDIM];
    int tid = threadIdx.x;

    if (blockIdx.x >= gemm_blocks) {
        int* l = (int*)hs;
        l[tid] = 0;
        __syncthreads();
        int base = (blockIdx.x - gemm_blocks) * 8192;
        #pragma unroll 4
        for (int u = 0; u < 32; ++u) {
            int i = base + u * 256 + tid;
            if (i < E) atomicAdd(&l[dst[i] >> 8], 1);
        }
        __syncthreads();
        if (l[tid]) atomicAdd(bcnt + tid, l[tid]);
        return;
    }

    int node0 = blockIdx.x * 64;
    int nv = min(64, N - node0);
    {
        const float4* hg = (const float4*)(h + (size_t)node0 * INDIM);
        const float4* Wg = (const float4*)W;
        float4* Ws4 = (float4*)Ws;
        #pragma unroll
        for (int i = 0; i < 8; ++i) {
            int idx = i * 256 + tid;
            int n = idx >> 5, j = idx & 31;
            float4 v = (n < nv) ? hg[n * 32 + j] : make_float4(0.f, 0.f, 0.f, 0.f);
            *(float4*)&hs[n * HPAD + j * 4] = v;
            Ws4[idx] = Wg[idx];
        }
    }
    __syncthreads();

    int fg = tid & 15, ng = tid >> 4;
    int f0 = fg * 4, tn = ng * 4;

    float acc[4][4];
    #pragma unroll
    for (int i = 0; i < 4; ++i)
        #pragma unroll
        for (int j = 0; j < 4; ++j) acc[i][j] = 0.f;

    #pragma unroll 4
    for (int k = 0; k < INDIM; k += 4) {
        float4 w0 = *(const float4*)&Ws[(k + 0) * OUTDIM + f0];
        float4 w1 = *(const float4*)&Ws[(k + 1) * OUTDIM + f0];
        float4 w2 = *(const float4*)&Ws[(k + 2) * OUTDIM + f0];
        float4 w3 = *(const float4*)&Ws[(k + 3) * OUTDIM + f0];
        float4 a0 = *(const float4*)&hs[(tn + 0) * HPAD + k];
        float4 a1 = *(const float4*)&hs[(tn + 1) * HPAD + k];
        float4 a2 = *(const float4*)&hs[(tn + 2) * HPAD + k];
        float4 a3 = *(const float4*)&hs[(tn + 3) * HPAD + k];
        #define ROW(r, ax, ay, az, aw) { \
            acc[r][0] += ax * w0.x + ay * w1.x + az * w2.x + aw * w3.x; \
            acc[r][1] += ax * w0.y + ay * w1.y + az * w2.y + aw * w3.y; \
            acc[r][2] += ax * w0.z + ay * w1.z + az * w2.z + aw * w3.z; \
            acc[r][3] += ax * w0.w + ay * w1.w + az * w2.w + aw * w3.w; }
        ROW(0, a0.x, a0.y, a0.z, a0.w)
        ROW(1, a1.x, a1.y, a1.z, a1.w)
        ROW(2, a2.x, a2.y, a2.z, a2.w)
        ROW(3, a3.x, a3.y, a3.z, a3.w)
        #undef ROW
    }

    #pragma unroll
    for (int i = 0; i < 4; ++i) {
        int node = node0 + tn + i;
        if (node < N) {
            ushort4 zb = make_ushort4(f2bf(acc[i][0]), f2bf(acc[i][1]),
                                      f2bf(acc[i][2]), f2bf(acc[i][3]));
            *(ushort4*)&z[(size_t)node * OUTDIM + f0] = zb;
        }
    }

    float4 was = *(const float4*)&Wa[f0];
    float4 wat = *(const float4*)&Wa[OUTDIM + f0];
    __syncthreads();
    float* sred = hs;
    float* tred = hs + 64;
    if (tid < 64) { sred[tid] = 0.f; tred[tid] = 0.f; }
    __syncthreads();
    #pragma unroll
    for (int i = 0; i < 4; ++i) {
        float ps = acc[i][0] * was.x + acc[i][1] * was.y +
                   acc[i][2] * was.z + acc[i][3] * was.w;
        float pt = acc[i][0] * wat.x + acc[i][1] * wat.y +
                   acc[i][2] * wat.z + acc[i][3] * wat.w;
        atomicAdd(&sred[tn + i], ps);
        atomicAdd(&tred[tn + i], pt);
    }
    __syncthreads();
    if (tid < 64 && node0 + tid < N) {
        s[node0 + tid] = sred[tid];
        t[node0 + tid] = tred[tid];
    }
}

// Kernel 2: scatter packed edges into bucket-contiguous regions.
// Local 256-scan of bcnt replaces the separate scan kernel; gcursor starts at 0.
__global__ __launch_bounds__(256) void bucket_scatter(
    const int* __restrict__ src, const int* __restrict__ dst,
    const int* __restrict__ bcnt, int* __restrict__ gcursor,
    int* __restrict__ esort, int E)
{
    __shared__ int lcnt[256];
    __shared__ int loff[256];
    __shared__ int gbase[256];
    __shared__ int lcur[256];
    __shared__ int bs[256];
    __shared__ int stage[SCHUNK];
    __shared__ unsigned char bof[SCHUNK];
    int tid = threadIdx.x;
    int base = blockIdx.x * SCHUNK;
    int ne = min(SCHUNK, E - base);

    // exclusive scan of global bucket counts (local replica)
    int bc = bcnt[tid];
    bs[tid] = bc;
    lcnt[tid] = 0;
    __syncthreads();
    for (int off = 1; off < 256; off <<= 1) {
        int add = (tid >= off) ? bs[tid - off] : 0;
        __syncthreads();
        bs[tid] += add;
        __syncthreads();
    }
    int bstart_own = bs[tid] - bc;   // exclusive prefix for own bucket

    int mys[8], myd[8];
    #pragma unroll
    for (int u = 0; u < 8; ++u) {
        int li = u * 256 + tid;
        if (li < ne) {
            mys[u] = src[base + li];
            myd[u] = dst[base + li];
            atomicAdd(&lcnt[myd[u] >> 8], 1);
        } else myd[u] = -1;
    }
    __syncthreads();

    loff[tid] = lcnt[tid];
    __syncthreads();
    for (int off = 1; off < 256; off <<= 1) {
        int add = (tid >= off) ? loff[tid - off] : 0;
        __syncthreads();
        loff[tid] += add;
        __syncthreads();
    }
    int excl = loff[tid] - lcnt[tid];
    loff[tid] = excl;
    lcur[tid] = excl;
    if (lcnt[tid] > 0)
        gbase[tid] = bstart_own + atomicAdd(gcursor + tid, lcnt[tid]);
    __syncthreads();

    #pragma unroll
    for (int u = 0; u < 8; ++u) {
        if (myd[u] >= 0) {
            int b = myd[u] >> 8;
            int p = atomicAdd(&lcur[b], 1);
            stage[p] = ((myd[u] & 255) << 24) | mys[u];
            bof[p] = (unsigned char)b;
        }
    }
    __syncthreads();

    for (int i = tid; i < ne; i += 256) {
        int b = bof[i];
        esort[gbase[b] + (i - loff[b])] = stage[i];
    }
}

// Kernel 3: one block per bucket: local histogram/scan/fill entirely in LDS.
// Re-derives bucket bounds from bcnt locally. Emits counts, offsets, sorted srcs.
__global__ __launch_bounds__(256) void bucket_fill(
    const int* __restrict__ esort, const int* __restrict__ bcnt,
    int* __restrict__ counts, int* __restrict__ offsets,
    int* __restrict__ srcs, int N)
{
    __shared__ int bs[256];
    __shared__ int cnt[256];
    __shared__ int off[256];
    __shared__ int cur[256];
    int tid = threadIdx.x;
    int b = blockIdx.x;

    int bc = bcnt[tid];
    bs[tid] = bc;
    cnt[tid] = 0;
    __syncthreads();
    for (int o = 1; o < 256; o <<= 1) {
        int add = (tid >= o) ? bs[tid - o] : 0;
        __syncthreads();
        bs[tid] += add;
        __syncthreads();
    }
    int e0 = (b > 0) ? bs[b - 1] : 0;
    int e1 = bs[b];
    int node0 = b << 8;

    for (int i = e0 + tid; i < e1; i += 256)
        atomicAdd(&cnt[((unsigned)esort[i]) >> 24], 1);
    __syncthreads();

    off[tid] = cnt[tid];
    __syncthreads();
    for (int o = 1; o < 256; o <<= 1) {
        int add = (tid >= o) ? off[tid - o] : 0;
        __syncthreads();
        off[tid] += add;
        __syncthreads();
    }
    int excl = off[tid] - cnt[tid];
    cur[tid] = excl;
    int node = node0 + tid;
    if (node < N) { counts[node] = cnt[tid]; offsets[node] = e0 + excl; }
    __syncthreads();

    for (int i = e0 + tid; i < e1; i += 256) {
        int pe = esort[i];
        int p = atomicAdd(&cur[((unsigned)pe) >> 24], 1);
        srcs[e0 + p] = pe & 0xFFFFFF;
    }
}

// Kernel 4: one wave per dst node. Fast path: no max-subtract (scores bounded,
// softmax is shift-invariant), 16-deep z-gather unroll.
__global__ __launch_bounds__(256) void aggregate(
    const unsigned short* __restrict__ z, const int* __restrict__ srcs,
    const float* __restrict__ s, const float* __restrict__ t,
    const int* __restrict__ offsets, const int* __restrict__ counts,
    float* __restrict__ out, int N)
{
    int wave = threadIdx.x >> 6;
    int lane = threadIdx.x & 63;
    int node = blockIdx.x * 4 + wave;
    if (node >= N) return;
    int start = offsets[node];
    int deg = counts[node];
    size_t orow = (size_t)node * OUTDIM + lane;
    if (deg == 0) { out[orow] = 0.f; return; }
    float tn = t[node];

    if (deg <= 64) {
        int sn = 0; float ex = 0.f;
        if (lane < deg) {
            sn = srcs[start + lane];
            ex = __expf(fmaxf(s[sn] + tn, 0.f));
        }
        float se = ex;
        #pragma unroll
        for (int off = 32; off; off >>= 1) se += __shfl_xor(se, off, 64);

        float acc = 0.f;
        int j = 0;
        for (; j + 16 <= deg; j += 16) {
            int si[16]; float ei[16]; unsigned short ai[16];
            #pragma unroll
            for (int u = 0; u < 16; ++u) {
                si[u] = __shfl(sn, j + u, 64);
                ei[u] = __shfl(ex, j + u, 64);
            }
            #pragma unroll
            for (int u = 0; u < 16; ++u)
                ai[u] = z[(size_t)si[u] * OUTDIM + lane];
            #pragma unroll
            for (int u = 0; u < 16; ++u)
                acc += ei[u] * bf2f(ai[u]);
        }
        for (; j + 4 <= deg; j += 4) {
            int s0 = __shfl(sn, j, 64),     s1 = __shfl(sn, j + 1, 64);
            int s2 = __shfl(sn, j + 2, 64), s3 = __shfl(sn, j + 3, 64);
            float e0 = __shfl(ex, j, 64),     e1 = __shfl(ex, j + 1, 64);
            float e2 = __shfl(ex, j + 2, 64), e3 = __shfl(ex, j + 3, 64);
            float a0 = bf2f(z[(size_t)s0 * OUTDIM + lane]);
            float a1 = bf2f(z[(size_t)s1 * OUTDIM + lane]);
            float a2 = bf2f(z[(size_t)s2 * OUTDIM + lane]);
            float a3 = bf2f(z[(size_t)s3 * OUTDIM + lane]);
            acc += e0 * a0; acc += e1 * a1; acc += e2 * a2; acc += e3 * a3;
        }
        for (; j < deg; ++j) {
            int sj = __shfl(sn, j, 64);
            float ej = __shfl(ex, j, 64);
            acc += ej * bf2f(z[(size_t)sj * OUTDIM + lane]);
        }
        out[orow] = fmaxf(acc / se, 0.f);
    } else {
        float mx = 0.f;
        for (int j = lane; j < deg; j += 64) {
            int sj = srcs[start + j];
            mx = fmaxf(mx, fmaxf(s[sj] + tn, 0.f));
        }
        #pragma unroll
        for (int off = 32; off; off >>= 1) mx = fmaxf(mx, __shfl_xor(mx, off, 64));
        float se = 0.f;
        for (int j = lane; j < deg; j += 64) {
            int sj = srcs[start + j];
            se += __expf(fmaxf(s[sj] + tn, 0.f) - mx);
        }
        #pragma unroll
        for (int off = 32; off; off >>= 1) se += __shfl_xor(se, off, 64);
        float acc = 0.f;
        for (int j = 0; j < deg; ++j) {
            int sj = srcs[start + j];
            float ej = __expf(fmaxf(s[sj] + tn, 0.f) - mx);
            acc += ej * bf2f(z[(size_t)sj * OUTDIM + lane]);
        }
        out[orow] = fmaxf(acc / se, 0.f);
    }
}

extern "C" void kernel_launch(void* const* d_in, const int* in_sizes, int n_in,
                              void* d_out, int out_size, void* d_ws, size_t ws_size,
                              hipStream_t stream) {
    const float* h  = (const float*)d_in[0];
    const float* W  = (const float*)d_in[1];
    const float* Wa = (const float*)d_in[2];
    const int* src  = (const int*)d_in[3];
    const int* dst  = (const int*)d_in[4];
    int N = in_sizes[0] / INDIM;
    int E = in_sizes[3];
    float* out = (float*)d_out;
    int nbuck = (N + 255) >> 8;   // <= 256

    char* ws = (char*)d_ws;
    unsigned short* z = (unsigned short*)ws;  ws += (size_t)N * OUTDIM * 2;
    float* s       = (float*)ws;  ws += (size_t)N * 4;
    float* t       = (float*)ws;  ws += (size_t)N * 4;
    int*   srcs    = (int*)ws;    ws += (size_t)E * 4;
    int*   counts  = (int*)ws;    ws += (size_t)N * 4;
    int*   offsets = (int*)ws;    ws += (size_t)N * 4;
    int*   esort   = (int*)ws;    ws += (size_t)E * 4;
    int*   bcnt    = (int*)ws;    ws += 256 * 4;
    int*   gcursor = (int*)ws;    ws += 256 * 4;

    int gemm_blocks = (N + 63) / 64;
    int count_blocks = (E + 8191) / 8192;

    hipMemsetAsync(bcnt, 0, 512 * sizeof(int), stream);  // bcnt + gcursor (adjacent)

    nt_count<<<gemm_blocks + count_blocks, 256, 0, stream>>>(
        h, W, Wa, z, s, t, dst, bcnt, N, E, gemm_blocks);
    bucket_scatter<<<(E + SCHUNK - 1) / SCHUNK, 256, 0, stream>>>(
        src, dst, bcnt, gcursor, esort, E);
    bucket_fill<<<nbuck, 256, 0, stream>>>(esort, bcnt, counts, offsets, srcs, N);
    aggregate<<<(N + 3) / 4, 256, 0, stream>>>(z, srcs, s, t, offsets, counts, out, N);
}